// Round 5
// baseline (156.776 us; speedup 1.0000x reference)
//
#include <hip/hip_runtime.h>
#include <hip/hip_bf16.h>

#define NROW 8192
#define CDIM 128
#define NCLS 10
#define NTILE 64           // 8192/128
#define NTRI 2080          // 64*65/2 upper-triangular tiles
#define NSEXT (NCLS * CDIM + NCLS)  // 1290: class sums + histogram
// 1/(T*ln2) = 10*log2(e)
#define EXP2_SCALE 14.4269504088896f

typedef _Float16 f16x8 __attribute__((ext_vector_type(8)));
typedef _Float16 f16x2 __attribute__((ext_vector_type(2)));
typedef float f32x4 __attribute__((ext_vector_type(4)));

// ---- fused: normalize -> xn,xnh; class-sum+hist block partials (pS,
// transposed for coalesced stage-2); zero the partial[] accumulator. ----
__global__ __launch_bounds__(256) void norm_csum_kernel(
    const float* __restrict__ x, const int* __restrict__ y,
    float* __restrict__ xn, _Float16* __restrict__ xnh,
    float* __restrict__ pS, float* __restrict__ partial) {
  __shared__ float s[NCLS * CDIM];
  __shared__ float hcnt[NCLS];
  const int t = threadIdx.x;
  const int l = t & 63, w = t >> 6;
  for (int i = t; i < NCLS * CDIM; i += 256) s[i] = 0.f;
  if (t < NCLS) hcnt[t] = 0.f;
  {  // zero this block's 2048-float slice of partial (col-side atomics)
    const f32x4 z = {0.f, 0.f, 0.f, 0.f};
    f32x4* p4 = (f32x4*)partial + blockIdx.x * 512;
    p4[t] = z;
    p4[t + 256] = z;
  }
  __syncthreads();
  const int row0 = blockIdx.x * 32 + w * 8;
  float2 v[8];
  int c[8];
#pragma unroll
  for (int r = 0; r < 8; ++r) {
    const int row = row0 + r;
    float2 xv = *(const float2*)&x[row * CDIM + l * 2];
    float ss = xv.x * xv.x + xv.y * xv.y;
#pragma unroll
    for (int off = 32; off; off >>= 1) ss += __shfl_xor(ss, off);
    const float inv = 1.f / fmaxf(sqrtf(ss), 1e-12f);
    xv.x *= inv;
    xv.y *= inv;
    v[r] = xv;
    c[r] = y[row];
    ((float2*)xn)[row * 64 + l] = xv;
    f16x2 h;
    h[0] = (_Float16)xv.x;
    h[1] = (_Float16)xv.y;
    ((f16x2*)xnh)[row * 64 + l] = h;
  }
#pragma unroll
  for (int r = 0; r < 8; ++r) {
    atomicAdd(&s[c[r] * CDIM + l * 2], v[r].x);
    atomicAdd(&s[c[r] * CDIM + l * 2 + 1], v[r].y);
  }
  if (l == 0) {
#pragma unroll
    for (int r = 0; r < 8; ++r) atomicAdd(&hcnt[c[r]], 1.f);
  }
  __syncthreads();
  for (int i = t; i < NCLS * CDIM; i += 256)
    pS[i * 256 + blockIdx.x] = s[i];
  if (t < NCLS) pS[(NCLS * CDIM + t) * 256 + blockIdx.x] = hcnt[t];
}

// ---- stage 2: one wave per output (1280 class-sums + 10 hist), coalesced
__global__ void csum2_kernel(const float* __restrict__ pS,
                             float* __restrict__ Sext) {
  const int w = threadIdx.x >> 6, l = threadIdx.x & 63;
  const int i = blockIdx.x * 4 + w;
  if (i >= NSEXT) return;
  const float4 v = *(const float4*)&pS[i * 256 + l * 4];
  float a = v.x + v.y + v.z + v.w;
#pragma unroll
  for (int off = 32; off; off >>= 1) a += __shfl_xor(a, off);
  if (l == 0) Sext[i] = a;
}

// ---- Gram GEMM + exp + row/col sums: one INDEPENDENT wave per 32x128
// slab (4 slabs/tile, triangular tile list). No LDS, no barriers: A and B
// fragments load straight from L2-resident xnh (coalesced 16 rows x 64B
// per instr). Row-sums are wave-local -> plain store to partial[row][bj];
// col-sums (symmetric side, s_ji = s_ij) are 4-way atomicAdd into
// partial[col][bi]. Slot ownership is disjoint (row-side: C >= bi;
// col-side: C < bi), so stores and atomics never collide. ----
__global__ __launch_bounds__(256, 4) void gemm_slab_kernel(
    const _Float16* __restrict__ xnh, float* __restrict__ partial) {
  const int w = threadIdx.x >> 6, l = threadIdx.x & 63;
  const int lane16 = l & 15, lanehi = l >> 4;
  const int W = blockIdx.x * 4 + w;
  const int tI = W >> 2, sr = W & 3;
  // triangular decode tI -> (bi, bj), bj >= bi
  const int m = (NTRI - 1) - tI;
  int r = (int)((sqrtf(8.f * (float)m + 1.f) - 1.f) * 0.5f);
  while ((r + 1) * (r + 2) / 2 <= m) ++r;
  while (r * (r + 1) / 2 > m) --r;
  const int k = m - r * (r + 1) / 2;
  const int bi = (NTILE - 1) - r, bj = (NTILE - 1) - k;
  const bool diag = (bi == bj);

  const int rowbase = bi * 128 + sr * 32;
  f16x8 a[2][4];
#pragma unroll
  for (int fm = 0; fm < 2; ++fm) {
    const int ra = rowbase + fm * 16 + lane16;
#pragma unroll
    for (int kk = 0; kk < 4; ++kk)
      a[fm][kk] = *(const f16x8*)&xnh[ra * CDIM + (kk * 4 + lanehi) * 8];
  }
  float pr[2][4];
#pragma unroll
  for (int fm = 0; fm < 2; ++fm)
#pragma unroll
    for (int e = 0; e < 4; ++e) pr[fm][e] = 0.f;

#pragma unroll
  for (int cg = 0; cg < 4; ++cg) {
    const int colbase = bj * 128 + cg * 32;
    f16x8 b[2][4];
#pragma unroll
    for (int fn = 0; fn < 2; ++fn) {
      const int rb = colbase + fn * 16 + lane16;
#pragma unroll
      for (int kk = 0; kk < 4; ++kk)
        b[fn][kk] = *(const f16x8*)&xnh[rb * CDIM + (kk * 4 + lanehi) * 8];
    }
    f32x4 acc[2][2];
#pragma unroll
    for (int fm = 0; fm < 2; ++fm)
#pragma unroll
      for (int fn = 0; fn < 2; ++fn) acc[fm][fn] = (f32x4){0.f, 0.f, 0.f, 0.f};
#pragma unroll
    for (int kk = 0; kk < 4; ++kk)
#pragma unroll
      for (int fm = 0; fm < 2; ++fm)
#pragma unroll
        for (int fn = 0; fn < 2; ++fn)
          acc[fm][fn] = __builtin_amdgcn_mfma_f32_16x16x32_f16(
              a[fm][kk], b[fn][kk], acc[fm][fn], 0, 0, 0);
    // fused epilogue for this col-group
#pragma unroll
    for (int fn = 0; fn < 2; ++fn) {
      float q = 0.f;
      const int col = colbase + fn * 16 + lane16;
#pragma unroll
      for (int fm = 0; fm < 2; ++fm) {
        const int row0r = rowbase + fm * 16 + lanehi * 4;
#pragma unroll
        for (int e = 0; e < 4; ++e) {
          float vv = exp2f(acc[fm][fn][e] * EXP2_SCALE);
          if (diag && (row0r + e) == col) vv = 0.f;
          pr[fm][e] += vv;
          q += vv;
        }
      }
      if (!diag) {
        q += __shfl_xor(q, 16);
        q += __shfl_xor(q, 32);
        if (l < 16)
          atomicAdd(&partial[(long)(colbase + fn * 16 + l) * 64 + bi], q);
      }
    }
  }
  // row-side: wave-local full row sums -> plain store
#pragma unroll
  for (int fm = 0; fm < 2; ++fm)
#pragma unroll
    for (int e = 0; e < 4; ++e) {
      float p = pr[fm][e];
      p += __shfl_xor(p, 1);
      p += __shfl_xor(p, 2);
      p += __shfl_xor(p, 4);
      p += __shfl_xor(p, 8);
      if (lane16 == 0)
        partial[(long)(rowbase + fm * 16 + lanehi * 4 + e) * 64 + bj] = p;
    }
}

// ---------------- final per-row loss + global reduce --------------------
__global__ void final_kernel(const float* __restrict__ xn,
                             const int* __restrict__ y,
                             const float* __restrict__ Sext,
                             const float* __restrict__ partial,
                             float* __restrict__ out) {
  const float* S = Sext;
  const float* histf = Sext + NCLS * CDIM;
  const int l = threadIdx.x & 63, w = threadIdx.x >> 6;
  const int waveid = blockIdx.x * 4 + w;  // 0..2047
  float accum = 0.f;
  for (int t = 0; t < 4; ++t) {
    const int row = waveid + 2048 * t;
    float d = partial[(long)row * 64 + l];  // coalesced col-block sums
    const int c = y[row];
    const float2 xv = *(const float2*)&xn[row * CDIM + l * 2];
    const float2 sv = *(const float2*)&S[c * CDIM + l * 2];
    float dot = xv.x * sv.x + xv.y * sv.y;
    float sf = xv.x * xv.x + xv.y * xv.y;
#pragma unroll
    for (int off = 32; off; off >>= 1) {
      d += __shfl_xor(d, off);
      dot += __shfl_xor(dot, off);
      sf += __shfl_xor(sf, off);
    }
    const float cntf = histf[c] - 1.f;
    float row_val = 0.f;
    if (cntf > 0.5f) {
      const float possum = dot - sf;  // exclude self term
      row_val = -(possum * 10.0f - cntf * logf(d)) / cntf;
    }
    accum += row_val;
  }
  __shared__ float bsum[4];
  if (l == 0) bsum[w] = accum;
  __syncthreads();
  if (threadIdx.x == 0)
    atomicAdd(out, bsum[0] + bsum[1] + bsum[2] + bsum[3]);
}

extern "C" void kernel_launch(void* const* d_in, const int* in_sizes, int n_in,
                              void* d_out, int out_size, void* d_ws,
                              size_t ws_size, hipStream_t stream) {
  const float* x = (const float*)d_in[0];
  const int* y = (const int*)d_in[1];
  float* out = (float*)d_out;
  char* ws = (char*)d_ws;

  float* xn = (float*)(ws);                     // 4 MB fp32 normalized
  _Float16* xnh = (_Float16*)(ws + (4 << 20));  // 2 MB f16 normalized
  float* partial = (float*)(ws + (6 << 20));    // 2 MB [8192][64]
  float* pS = (float*)(ws + (8 << 20));         // 1.32 MB [1290][256]
  float* Sext = (float*)(ws + (10 << 20));      // 5.2 KB class sums + hist

  hipMemsetAsync(out, 0, sizeof(float), stream);
  norm_csum_kernel<<<256, 256, 0, stream>>>(x, y, xn, xnh, pS, partial);
  csum2_kernel<<<(NSEXT + 3) / 4, 256, 0, stream>>>(pS, Sext);
  gemm_slab_kernel<<<NTRI, 256, 0, stream>>>(xnh, partial);
  final_kernel<<<512, 256, 0, stream>>>(xn, y, Sext, partial, out);
}

// Round 6
// 144.958 us; speedup vs baseline: 1.0815x; 1.0815x over previous
//
#include <hip/hip_runtime.h>
#include <hip/hip_bf16.h>

#define NROW 8192
#define CDIM 128
#define NCLS 10
#define NTILE 64           // 8192/128
#define NTRI 2080          // 64*65/2 upper-triangular tiles
#define NBCS 512           // norm_csum block count
#define NSEXT (NCLS * CDIM + NCLS)  // 1290: class sums + histogram
// 1/(T*ln2) = 10*log2(e)
#define EXP2_SCALE 14.4269504088896f

typedef _Float16 f16x8 __attribute__((ext_vector_type(8)));
typedef _Float16 f16x2 __attribute__((ext_vector_type(2)));
typedef float f32x4 __attribute__((ext_vector_type(4)));

typedef __attribute__((address_space(1))) const unsigned int gu32;
typedef __attribute__((address_space(3))) unsigned int lu32;

__device__ __forceinline__ void gload_lds16(const _Float16* g, _Float16* l) {
  __builtin_amdgcn_global_load_lds((gu32*)g, (lu32*)l, 16, 0, 0);
}

// ---- fused: normalize -> xn,xnh; class-sum+hist block partials (pS,
// transposed for coalesced stage-2); zero the partial[] accumulator. ----
__global__ __launch_bounds__(256) void norm_csum_kernel(
    const float* __restrict__ x, const int* __restrict__ y,
    float* __restrict__ xn, _Float16* __restrict__ xnh,
    float* __restrict__ pS, float* __restrict__ partial) {
  __shared__ float s[NCLS * CDIM];
  __shared__ float hcnt[NCLS];
  const int t = threadIdx.x;
  const int l = t & 63, w = t >> 6;
  for (int i = t; i < NCLS * CDIM; i += 256) s[i] = 0.f;
  if (t < NCLS) hcnt[t] = 0.f;
  // zero this block's 4KB slice of partial (atomic accumulator)
  ((f32x4*)partial)[blockIdx.x * 256 + t] = (f32x4){0.f, 0.f, 0.f, 0.f};
  __syncthreads();
  const int row0 = blockIdx.x * 16 + w * 4;
  float2 v[4];
  int c[4];
#pragma unroll
  for (int r = 0; r < 4; ++r) {
    const int row = row0 + r;
    float2 xv = *(const float2*)&x[row * CDIM + l * 2];
    float ss = xv.x * xv.x + xv.y * xv.y;
#pragma unroll
    for (int off = 32; off; off >>= 1) ss += __shfl_xor(ss, off);
    const float inv = 1.f / fmaxf(sqrtf(ss), 1e-12f);
    xv.x *= inv;
    xv.y *= inv;
    v[r] = xv;
    c[r] = y[row];
    ((float2*)xn)[row * 64 + l] = xv;
    f16x2 h;
    h[0] = (_Float16)xv.x;
    h[1] = (_Float16)xv.y;
    ((f16x2*)xnh)[row * 64 + l] = h;
  }
#pragma unroll
  for (int r = 0; r < 4; ++r) {
    atomicAdd(&s[c[r] * CDIM + l * 2], v[r].x);
    atomicAdd(&s[c[r] * CDIM + l * 2 + 1], v[r].y);
  }
  if (l == 0) {
#pragma unroll
    for (int r = 0; r < 4; ++r) atomicAdd(&hcnt[c[r]], 1.f);
  }
  __syncthreads();
  for (int i = t; i < NCLS * CDIM; i += 256)
    pS[i * NBCS + blockIdx.x] = s[i];
  if (t < NCLS) pS[(NCLS * CDIM + t) * NBCS + blockIdx.x] = hcnt[t];
}

// ---- stage 2: one wave per output (1280 class-sums + 10 hist) ----------
__global__ void csum2_kernel(const float* __restrict__ pS,
                             float* __restrict__ Sext) {
  const int w = threadIdx.x >> 6, l = threadIdx.x & 63;
  const int i = blockIdx.x * 4 + w;
  if (i >= NSEXT) return;
  const f32x4* p = (const f32x4*)&pS[i * NBCS];
  const f32x4 v0 = p[l], v1 = p[l + 64];
  float a = v0.x + v0.y + v0.z + v0.w + v1.x + v1.y + v1.z + v1.w;
#pragma unroll
  for (int off = 32; off; off >>= 1) a += __shfl_xor(a, off);
  if (l == 0) Sext[i] = a;
}

// ---- Gram GEMM + exp + row/col sums. Hybrid structure:
//  * B tile (128x128 f16, 32KB) staged to LDS ONCE per block via
//    global_load_lds, XOR-swizzled by pre-swizzling the global source
//    (shared by all 4 waves -> no redundant L2 traffic).
//  * A: each wave owns a DISTINCT 32-row slab in registers (direct
//    coalesced global loads; no LDS, no redundancy).
//  * ONE barrier total; afterwards waves run free.
//  * Row-sums are wave-complete -> plain store to partial[row][bj].
//    Col-sums (symmetry, s_ji=s_ij) -> global atomicAdd partial[col][bi]
//    (4-way wave contention, zero-inited by norm_csum).
//  * LDS 32KB -> 4 blocks/CU, 16 waves/CU. ----
__global__ __launch_bounds__(256, 4) void gemm_exp_kernel(
    const _Float16* __restrict__ xnh, float* __restrict__ partial) {
  __shared__ _Float16 Bs[128 * 128];

  const int tid = threadIdx.x;
  const int l = tid & 63, w = tid >> 6;
  const int lane16 = l & 15, lanehi = l >> 4;

  // triangular decode blockIdx.x -> (bi, bj), bj >= bi
  const int m = (NTRI - 1) - blockIdx.x;
  int r = (int)((sqrtf(8.f * (float)m + 1.f) - 1.f) * 0.5f);
  while ((r + 1) * (r + 2) / 2 <= m) ++r;
  while (r * (r + 1) / 2 > m) --r;
  const int k = m - r * (r + 1) / 2;
  const int bi = (NTILE - 1) - r, bj = (NTILE - 1) - k;
  const bool diag = (bi == bj);

  // stage B tile: 32 x 1KB chunks, 8 per wave
  {
    const _Float16* srcb = xnh + (long)bj * 128 * CDIM;
#pragma unroll
    for (int i = 0; i < 8; ++i) {
      const int rg = (w * 8 + i) * 4;      // first row of 1KB chunk
      const int rl = rg + lanehi;          // row this lane fetches
      const int csrc = lane16 ^ (rl & 7);  // pre-swizzled source chunk
      gload_lds16(&srcb[rl * CDIM + csrc * 8], &Bs[rg * 128]);
    }
  }
  // A slab for this wave: rows [bi*128 + w*32, +32), full K in registers
  const int rowbase = bi * 128 + w * 32;
  f16x8 a[2][4];
#pragma unroll
  for (int fm = 0; fm < 2; ++fm) {
    const int ra = rowbase + fm * 16 + lane16;
#pragma unroll
    for (int kk = 0; kk < 4; ++kk)
      a[fm][kk] = *(const f16x8*)&xnh[ra * CDIM + (kk * 4 + lanehi) * 8];
  }
  __syncthreads();

  float pr[2][4];
#pragma unroll
  for (int fm = 0; fm < 2; ++fm)
#pragma unroll
    for (int e = 0; e < 4; ++e) pr[fm][e] = 0.f;

#pragma unroll
  for (int cg = 0; cg < 4; ++cg) {
    f16x8 b[2][4];
#pragma unroll
    for (int fn = 0; fn < 2; ++fn) {
      const int rb = cg * 32 + fn * 16 + lane16;  // row within B tile
#pragma unroll
      for (int kk = 0; kk < 4; ++kk) {
        const int cb = (kk * 4 + lanehi) ^ (rb & 7);
        b[fn][kk] = *(const f16x8*)&Bs[rb * 128 + cb * 8];
      }
    }
    f32x4 acc[2][2];
#pragma unroll
    for (int fm = 0; fm < 2; ++fm)
#pragma unroll
      for (int fn = 0; fn < 2; ++fn) acc[fm][fn] = (f32x4){0.f, 0.f, 0.f, 0.f};
#pragma unroll
    for (int kk = 0; kk < 4; ++kk)
#pragma unroll
      for (int fm = 0; fm < 2; ++fm)
#pragma unroll
        for (int fn = 0; fn < 2; ++fn)
          acc[fm][fn] = __builtin_amdgcn_mfma_f32_16x16x32_f16(
              a[fm][kk], b[fn][kk], acc[fm][fn], 0, 0, 0);
    // fused epilogue for this col-group
#pragma unroll
    for (int fn = 0; fn < 2; ++fn) {
      float q = 0.f;
      const int col = bj * 128 + cg * 32 + fn * 16 + lane16;
#pragma unroll
      for (int fm = 0; fm < 2; ++fm) {
        const int row0r = rowbase + fm * 16 + lanehi * 4;
#pragma unroll
        for (int e = 0; e < 4; ++e) {
          float vv = exp2f(acc[fm][fn][e] * EXP2_SCALE);
          if (diag && (row0r + e) == col) vv = 0.f;
          pr[fm][e] += vv;
          q += vv;
        }
      }
      if (!diag) {
        q += __shfl_xor(q, 16);
        q += __shfl_xor(q, 32);
        if (l < 16) atomicAdd(&partial[(long)(col)*64 + bi], q);
      }
    }
  }
  // row-side: wave-complete row sums -> plain store
#pragma unroll
  for (int fm = 0; fm < 2; ++fm)
#pragma unroll
    for (int e = 0; e < 4; ++e) {
      float p = pr[fm][e];
      p += __shfl_xor(p, 1);
      p += __shfl_xor(p, 2);
      p += __shfl_xor(p, 4);
      p += __shfl_xor(p, 8);
      if (lane16 == 0)
        partial[(long)(rowbase + fm * 16 + lanehi * 4 + e) * 64 + bj] = p;
    }
}

// ---------------- final per-row loss + global reduce --------------------
__global__ __launch_bounds__(256) void final_kernel(
    const float* __restrict__ xn, const int* __restrict__ y,
    const float* __restrict__ Sext, const float* __restrict__ partial,
    float* __restrict__ out) {
  const float* S = Sext;
  const float* histf = Sext + NCLS * CDIM;
  const int l = threadIdx.x & 63, w = threadIdx.x >> 6;
  const int waveid = blockIdx.x * 4 + w;  // 0..2047
  float accum = 0.f;
  for (int t = 0; t < 4; ++t) {
    const int row = waveid + 2048 * t;
    float d = partial[(long)row * 64 + l];  // coalesced col-block sums
    const int c = y[row];
    const float2 xv = *(const float2*)&xn[row * CDIM + l * 2];
    const float2 sv = *(const float2*)&S[c * CDIM + l * 2];
    float dot = xv.x * sv.x + xv.y * sv.y;
    float sf = xv.x * xv.x + xv.y * xv.y;
#pragma unroll
    for (int off = 32; off; off >>= 1) {
      d += __shfl_xor(d, off);
      dot += __shfl_xor(dot, off);
      sf += __shfl_xor(sf, off);
    }
    const float cntf = histf[c] - 1.f;
    float row_val = 0.f;
    if (cntf > 0.5f) {
      const float possum = dot - sf;  // exclude self term
      row_val = -(possum * 10.0f - cntf * logf(d)) / cntf;
    }
    accum += row_val;
  }
  __shared__ float bsum[4];
  if (l == 0) bsum[w] = accum;
  __syncthreads();
  if (threadIdx.x == 0)
    atomicAdd(out, bsum[0] + bsum[1] + bsum[2] + bsum[3]);
}

extern "C" void kernel_launch(void* const* d_in, const int* in_sizes, int n_in,
                              void* d_out, int out_size, void* d_ws,
                              size_t ws_size, hipStream_t stream) {
  const float* x = (const float*)d_in[0];
  const int* y = (const int*)d_in[1];
  float* out = (float*)d_out;
  char* ws = (char*)d_ws;

  float* xn = (float*)(ws);                     // 4 MB fp32 normalized
  _Float16* xnh = (_Float16*)(ws + (4 << 20));  // 2 MB f16 normalized
  float* partial = (float*)(ws + (6 << 20));    // 2 MB [8192][64]
  float* pS = (float*)(ws + (8 << 20));         // 2.64 MB [1290][512]
  float* Sext = (float*)(ws + (11 << 20));      // 5.2 KB class sums + hist

  hipMemsetAsync(out, 0, sizeof(float), stream);
  norm_csum_kernel<<<NBCS, 256, 0, stream>>>(x, y, xn, xnh, pS, partial);
  csum2_kernel<<<(NSEXT + 3) / 4, 256, 0, stream>>>(pS, Sext);
  gemm_exp_kernel<<<NTRI, 256, 0, stream>>>(xnh, partial);
  final_kernel<<<512, 256, 0, stream>>>(xn, y, Sext, partial, out);
}

// Round 8
// 125.249 us; speedup vs baseline: 1.2517x; 1.1574x over previous
//
#include <hip/hip_runtime.h>
#include <hip/hip_bf16.h>

#define NROW 8192
#define CDIM 128
#define NCLS 10
#define NTILE 64           // 8192/128 col-blocks
#define NBCS 512           // norm_csum block count
#define NSEXT (NCLS * CDIM + NCLS)  // 1290: class sums + histogram
// 1/(T*ln2) = 10*log2(e)
#define EXP2_SCALE 14.4269504088896f

typedef _Float16 f16x8 __attribute__((ext_vector_type(8)));
typedef _Float16 f16x2 __attribute__((ext_vector_type(2)));
typedef float f32x4 __attribute__((ext_vector_type(4)));

typedef __attribute__((address_space(1))) const unsigned int gu32;
typedef __attribute__((address_space(3))) unsigned int lu32;

__device__ __forceinline__ void gload_lds16(const _Float16* g, _Float16* l) {
  __builtin_amdgcn_global_load_lds((gu32*)g, (lu32*)l, 16, 0, 0);
}

// ---- fused: normalize -> xn,xnh; class-sum+hist block partials (pS,
// transposed for coalesced stage-2). ----
__global__ __launch_bounds__(256) void norm_csum_kernel(
    const float* __restrict__ x, const int* __restrict__ y,
    float* __restrict__ xn, _Float16* __restrict__ xnh,
    float* __restrict__ pS) {
  __shared__ float s[NCLS * CDIM];
  __shared__ float hcnt[NCLS];
  const int t = threadIdx.x;
  const int l = t & 63, w = t >> 6;
  for (int i = t; i < NCLS * CDIM; i += 256) s[i] = 0.f;
  if (t < NCLS) hcnt[t] = 0.f;
  __syncthreads();
  const int row0 = blockIdx.x * 16 + w * 4;
  float2 v[4];
  int c[4];
#pragma unroll
  for (int r = 0; r < 4; ++r) {
    const int row = row0 + r;
    float2 xv = *(const float2*)&x[row * CDIM + l * 2];
    float ss = xv.x * xv.x + xv.y * xv.y;
#pragma unroll
    for (int off = 32; off; off >>= 1) ss += __shfl_xor(ss, off);
    const float inv = 1.f / fmaxf(sqrtf(ss), 1e-12f);
    xv.x *= inv;
    xv.y *= inv;
    v[r] = xv;
    c[r] = y[row];
    ((float2*)xn)[row * 64 + l] = xv;
    f16x2 h;
    h[0] = (_Float16)xv.x;
    h[1] = (_Float16)xv.y;
    ((f16x2*)xnh)[row * 64 + l] = h;
  }
#pragma unroll
  for (int r = 0; r < 4; ++r) {
    atomicAdd(&s[c[r] * CDIM + l * 2], v[r].x);
    atomicAdd(&s[c[r] * CDIM + l * 2 + 1], v[r].y);
  }
  if (l == 0) {
#pragma unroll
    for (int r = 0; r < 4; ++r) atomicAdd(&hcnt[c[r]], 1.f);
  }
  __syncthreads();
  for (int i = t; i < NCLS * CDIM; i += 256)
    pS[i * NBCS + blockIdx.x] = s[i];
  if (t < NCLS) pS[(NCLS * CDIM + t) * NBCS + blockIdx.x] = hcnt[t];
}

// ---- stage 2: one wave per output (1280 class-sums + 10 hist) ----------
__global__ void csum2_kernel(const float* __restrict__ pS,
                             float* __restrict__ Sext) {
  const int w = threadIdx.x >> 6, l = threadIdx.x & 63;
  const int i = blockIdx.x * 4 + w;
  if (i >= NSEXT) return;
  const f32x4* p = (const f32x4*)&pS[i * NBCS];
  const f32x4 v0 = p[l], v1 = p[l + 64];
  float a = v0.x + v0.y + v0.z + v0.w + v1.x + v1.y + v1.z + v1.w;
#pragma unroll
  for (int off = 32; off; off >>= 1) a += __shfl_xor(a, off);
  if (l == 0) Sext[i] = a;
}

// ---- Gram GEMM + exp + row-sum. FULL matrix (no symmetry, no atomics).
// Block tile 256 rows x 128 cols; 4 waves, each owns 64 rows x 128 cols.
//  * B tile (128 rows x K, 32KB) staged to LDS once per block via
//    global_load_lds, XOR-swizzled by pre-swizzling the global source.
//  * A: each wave's 64-row slab lives in registers (direct global loads).
//  * SWAPPED MFMA operands: acc = mfma(b, a) puts the reduction axis (j)
//    in the register/lanehi dimension -> row-sum over j is in-register
//    adds + 2 shuffles per 16-row group (no LDS reductions, no atomics).
//  * acc[fm][fn]: j = cg*32 + fn*16 + lanehi*4 + e, i = fm*16 + lane16.
//  * Row-sums stored directly: partial[i][colblock], one writer each. ----
__global__ __launch_bounds__(256, 3) void gemm_exp_kernel(
    const _Float16* __restrict__ xnh, float* __restrict__ partial) {
  __shared__ _Float16 Bs[128 * 128];

  const int tid = threadIdx.x;
  const int l = tid & 63, w = tid >> 6;
  const int lane16 = l & 15, lanehi = l >> 4;
  const int cb = blockIdx.x;   // col-block 0..63 (128 cols)
  const int rb = blockIdx.y;   // row-block 0..31 (256 rows)

  // stage B tile: 32 x 1KB chunks, 8 per wave
  {
    const _Float16* srcb = xnh + (long)cb * 128 * CDIM;
#pragma unroll
    for (int i = 0; i < 8; ++i) {
      const int rg = (w * 8 + i) * 4;      // first row of 1KB chunk
      const int rl = rg + lanehi;          // row this lane fetches
      const int csrc = lane16 ^ (rl & 7);  // pre-swizzled source chunk
      gload_lds16(&srcb[rl * CDIM + csrc * 8], &Bs[rg * 128]);
    }
  }
  // A slab for this wave: rows [rb*256 + w*64, +64), full K in registers
  const int rowbase = rb * 256 + w * 64;
  f16x8 a[4][4];
#pragma unroll
  for (int fm = 0; fm < 4; ++fm) {
    const int ra = rowbase + fm * 16 + lane16;
#pragma unroll
    for (int kk = 0; kk < 4; ++kk)
      a[fm][kk] = *(const f16x8*)&xnh[ra * CDIM + (kk * 4 + lanehi) * 8];
  }
  __syncthreads();

  const bool diagt = ((cb >> 1) == rb);  // tile touches the diagonal
  float rowsum[4] = {0.f, 0.f, 0.f, 0.f};

#pragma unroll
  for (int cg = 0; cg < 4; ++cg) {
    f16x8 b[2][4];
#pragma unroll
    for (int fn = 0; fn < 2; ++fn) {
      const int rbr = cg * 32 + fn * 16 + lane16;  // row within B tile
#pragma unroll
      for (int kk = 0; kk < 4; ++kk) {
        const int cbk = (kk * 4 + lanehi) ^ (rbr & 7);
        b[fn][kk] = *(const f16x8*)&Bs[rbr * 128 + cbk * 8];
      }
    }
    f32x4 acc[4][2];
#pragma unroll
    for (int fm = 0; fm < 4; ++fm)
#pragma unroll
      for (int fn = 0; fn < 2; ++fn) acc[fm][fn] = (f32x4){0.f, 0.f, 0.f, 0.f};
#pragma unroll
    for (int kk = 0; kk < 4; ++kk)
#pragma unroll
      for (int fm = 0; fm < 4; ++fm)
#pragma unroll
        for (int fn = 0; fn < 2; ++fn)
          acc[fm][fn] = __builtin_amdgcn_mfma_f32_16x16x32_f16(
              b[fn][kk], a[fm][kk], acc[fm][fn], 0, 0, 0);
    // fused epilogue: exp2 + in-register row accumulation (j is local)
#pragma unroll
    for (int fm = 0; fm < 4; ++fm) {
      const int gi = rowbase + fm * 16 + lane16;
#pragma unroll
      for (int fn = 0; fn < 2; ++fn) {
        const int j0 = cb * 128 + cg * 32 + fn * 16 + lanehi * 4;
#pragma unroll
        for (int e = 0; e < 4; ++e) {
          float vv = exp2f(acc[fm][fn][e] * EXP2_SCALE);
          if (diagt && gi == (j0 + e)) vv = 0.f;
          rowsum[fm] += vv;
        }
      }
    }
  }
  // reduce across the 4 lanehi groups; lanes 0-15 store 16 rows each
#pragma unroll
  for (int fm = 0; fm < 4; ++fm) {
    float s = rowsum[fm];
    s += __shfl_xor(s, 16);
    s += __shfl_xor(s, 32);
    if (l < 16) partial[(long)(rowbase + fm * 16 + l) * 64 + cb] = s;
  }
}

// ---------------- final per-row loss + global reduce --------------------
__global__ __launch_bounds__(256) void final_kernel(
    const float* __restrict__ xn, const int* __restrict__ y,
    const float* __restrict__ Sext, const float* __restrict__ partial,
    float* __restrict__ out) {
  const float* S = Sext;
  const float* histf = Sext + NCLS * CDIM;
  const int l = threadIdx.x & 63, w = threadIdx.x >> 6;
  const int waveid = blockIdx.x * 4 + w;  // 0..2047
  float accum = 0.f;
  for (int t = 0; t < 4; ++t) {
    const int row = waveid + 2048 * t;
    float d = partial[(long)row * 64 + l];  // coalesced col-block sums
    const int c = y[row];
    const float2 xv = *(const float2*)&xn[row * CDIM + l * 2];
    const float2 sv = *(const float2*)&S[c * CDIM + l * 2];
    float dot = xv.x * sv.x + xv.y * sv.y;
    float sf = xv.x * xv.x + xv.y * xv.y;
#pragma unroll
    for (int off = 32; off; off >>= 1) {
      d += __shfl_xor(d, off);
      dot += __shfl_xor(dot, off);
      sf += __shfl_xor(sf, off);
    }
    const float cntf = histf[c] - 1.f;
    float row_val = 0.f;
    if (cntf > 0.5f) {
      const float possum = dot - sf;  // exclude self term
      row_val = -(possum * 10.0f - cntf * logf(d)) / cntf;
    }
    accum += row_val;
  }
  __shared__ float bsum[4];
  if (l == 0) bsum[w] = accum;
  __syncthreads();
  if (threadIdx.x == 0)
    atomicAdd(out, bsum[0] + bsum[1] + bsum[2] + bsum[3]);
}

extern "C" void kernel_launch(void* const* d_in, const int* in_sizes, int n_in,
                              void* d_out, int out_size, void* d_ws,
                              size_t ws_size, hipStream_t stream) {
  const float* x = (const float*)d_in[0];
  const int* y = (const int*)d_in[1];
  float* out = (float*)d_out;
  char* ws = (char*)d_ws;

  float* xn = (float*)(ws);                     // 4 MB fp32 normalized
  _Float16* xnh = (_Float16*)(ws + (4 << 20));  // 2 MB f16 normalized
  float* partial = (float*)(ws + (6 << 20));    // 2 MB [8192][64]
  float* pS = (float*)(ws + (8 << 20));         // 2.64 MB [1290][512]
  float* Sext = (float*)(ws + (11 << 20));      // 5.2 KB class sums + hist

  hipMemsetAsync(out, 0, sizeof(float), stream);
  norm_csum_kernel<<<NBCS, 256, 0, stream>>>(x, y, xn, xnh, pS);
  csum2_kernel<<<(NSEXT + 3) / 4, 256, 0, stream>>>(pS, Sext);
  gemm_exp_kernel<<<dim3(NTILE, 32), 256, 0, stream>>>(xnh, partial);
  final_kernel<<<512, 256, 0, stream>>>(xn, y, Sext, partial, out);
}

// Round 9
// 119.300 us; speedup vs baseline: 1.3141x; 1.0499x over previous
//
#include <hip/hip_runtime.h>
#include <hip/hip_bf16.h>

#define NROW 8192
#define CDIM 128
#define NCLS 10
#define NCJG 16            // col-groups (512 cols each)
#define NBCS 512           // norm_csum block count
#define NSEXT (NCLS * CDIM + NCLS)  // 1290: class sums + histogram
// 1/(T*ln2) = 10*log2(e)
#define EXP2_SCALE 14.4269504088896f

typedef _Float16 f16x8 __attribute__((ext_vector_type(8)));
typedef _Float16 f16x2 __attribute__((ext_vector_type(2)));
typedef float f32x4 __attribute__((ext_vector_type(4)));

typedef __attribute__((address_space(1))) const unsigned int gu32;
typedef __attribute__((address_space(3))) unsigned int lu32;

__device__ __forceinline__ void gload_lds16(const _Float16* g, _Float16* l) {
  __builtin_amdgcn_global_load_lds((gu32*)g, (lu32*)l, 16, 0, 0);
}

// ---- fused: normalize -> xn,xnh; class-sum+hist block partials (pS,
// transposed for coalesced stage-2). ----
__global__ __launch_bounds__(256) void norm_csum_kernel(
    const float* __restrict__ x, const int* __restrict__ y,
    float* __restrict__ xn, _Float16* __restrict__ xnh,
    float* __restrict__ pS) {
  __shared__ float s[NCLS * CDIM];
  __shared__ float hcnt[NCLS];
  const int t = threadIdx.x;
  const int l = t & 63, w = t >> 6;
  for (int i = t; i < NCLS * CDIM; i += 256) s[i] = 0.f;
  if (t < NCLS) hcnt[t] = 0.f;
  __syncthreads();
  const int row0 = blockIdx.x * 16 + w * 4;
  float2 v[4];
  int c[4];
#pragma unroll
  for (int r = 0; r < 4; ++r) {
    const int row = row0 + r;
    float2 xv = *(const float2*)&x[row * CDIM + l * 2];
    float ss = xv.x * xv.x + xv.y * xv.y;
#pragma unroll
    for (int off = 32; off; off >>= 1) ss += __shfl_xor(ss, off);
    const float inv = 1.f / fmaxf(sqrtf(ss), 1e-12f);
    xv.x *= inv;
    xv.y *= inv;
    v[r] = xv;
    c[r] = y[row];
    ((float2*)xn)[row * 64 + l] = xv;
    f16x2 h;
    h[0] = (_Float16)xv.x;
    h[1] = (_Float16)xv.y;
    ((f16x2*)xnh)[row * 64 + l] = h;
  }
#pragma unroll
  for (int r = 0; r < 4; ++r) {
    atomicAdd(&s[c[r] * CDIM + l * 2], v[r].x);
    atomicAdd(&s[c[r] * CDIM + l * 2 + 1], v[r].y);
  }
  if (l == 0) {
#pragma unroll
    for (int r = 0; r < 4; ++r) atomicAdd(&hcnt[c[r]], 1.f);
  }
  __syncthreads();
  for (int i = t; i < NCLS * CDIM; i += 256)
    pS[i * NBCS + blockIdx.x] = s[i];
  if (t < NCLS) pS[(NCLS * CDIM + t) * NBCS + blockIdx.x] = hcnt[t];
}

// ---- stage 2: one wave per output (1280 class-sums + 10 hist) ----------
__global__ void csum2_kernel(const float* __restrict__ pS,
                             float* __restrict__ Sext) {
  const int w = threadIdx.x >> 6, l = threadIdx.x & 63;
  const int i = blockIdx.x * 4 + w;
  if (i >= NSEXT) return;
  const f32x4* p = (const f32x4*)&pS[i * NBCS];
  const f32x4 v0 = p[l], v1 = p[l + 64];
  float a = v0.x + v0.y + v0.z + v0.w + v1.x + v1.y + v1.z + v1.w;
#pragma unroll
  for (int off = 32; off; off >>= 1) a += __shfl_xor(a, off);
  if (l == 0) Sext[i] = a;
}

// ---- Gram GEMM + exp + row-sum. Multi-tile: each block = 256 rows x
// 512 cols = 4 B-tiles looped with single-buffer LDS staging (32KB ->
// 4 blocks/CU; inter-block overlap hides the stage/drain).
//  * A: each wave owns 64 rows x 128 K in regs, loaded ONCE.
//  * B tile staged via global_load_lds, XOR-swizzle via pre-swizzled
//    global source; read side applies the same involution.
//  * SWAPPED MFMA (acc = mfma(b,a)): output col (lane16) = i, output
//    row (lanehi*4+e) = j -> row-sum over j is in-register adds;
//    rowsum[fm] accumulates across ALL 4 tiles.
//  * One coalesced 256B store per wave: partial[cjg][rowbase+l]. ----
__global__ __launch_bounds__(256, 4) void gemm_exp_kernel(
    const _Float16* __restrict__ xnh, float* __restrict__ partial) {
  __shared__ _Float16 Bs[128 * 128];

  const int tid = threadIdx.x;
  const int l = tid & 63, w = tid >> 6;
  const int lane16 = l & 15, lanehi = l >> 4;
  const int cjg = blockIdx.x;  // 0..15  (512-col group)
  const int rb = blockIdx.y;   // 0..31  (256-row block)

  // A slab for this wave: rows [rb*256 + w*64, +64), full K in registers
  const int rowbase = rb * 256 + w * 64;
  f16x8 a[4][4];
#pragma unroll
  for (int fm = 0; fm < 4; ++fm) {
    const int ra = rowbase + fm * 16 + lane16;
#pragma unroll
    for (int kk = 0; kk < 4; ++kk)
      a[fm][kk] = *(const f16x8*)&xnh[ra * CDIM + (kk * 4 + lanehi) * 8];
  }

  const int myrowblk = rowbase >> 7;  // 128-col-block containing our rows
  float rowsum[4] = {0.f, 0.f, 0.f, 0.f};

  for (int t = 0; t < 4; ++t) {
    const int cb = cjg * 4 + t;  // global 128-col block
    // stage B tile: 32 x 1KB chunks, 8 per wave
    {
      const _Float16* srcb = xnh + (long)cb * 128 * CDIM;
#pragma unroll
      for (int i = 0; i < 8; ++i) {
        const int rg = (w * 8 + i) * 4;      // first row of 1KB chunk
        const int rl = rg + lanehi;          // row this lane fetches
        const int csrc = lane16 ^ (rl & 7);  // pre-swizzled source chunk
        gload_lds16(&srcb[rl * CDIM + csrc * 8], &Bs[rg * 128]);
      }
    }
    __syncthreads();  // drains vmcnt+lgkmcnt: staged tile visible

    const bool dt = (cb == myrowblk);  // this tile touches the diagonal
#pragma unroll
    for (int fn = 0; fn < 8; ++fn) {
      f16x8 b[4];
      const int rbr = fn * 16 + lane16;  // j-row within B tile
#pragma unroll
      for (int kk = 0; kk < 4; ++kk) {
        const int cbk = (kk * 4 + lanehi) ^ (rbr & 7);
        b[kk] = *(const f16x8*)&Bs[rbr * 128 + cbk * 8];
      }
      f32x4 acc[4];
#pragma unroll
      for (int fm = 0; fm < 4; ++fm) acc[fm] = (f32x4){0.f, 0.f, 0.f, 0.f};
#pragma unroll
      for (int kk = 0; kk < 4; ++kk)
#pragma unroll
        for (int fm = 0; fm < 4; ++fm)
          acc[fm] = __builtin_amdgcn_mfma_f32_16x16x32_f16(
              b[kk], a[fm][kk], acc[fm], 0, 0, 0);
      if (dt) {
#pragma unroll
        for (int fm = 0; fm < 4; ++fm) {
          const int gi = rowbase + fm * 16 + lane16;
          const int j0 = cb * 128 + fn * 16 + lanehi * 4;
#pragma unroll
          for (int e = 0; e < 4; ++e) {
            float vv = exp2f(acc[fm][e] * EXP2_SCALE);
            if (gi == (j0 + e)) vv = 0.f;
            rowsum[fm] += vv;
          }
        }
      } else {
#pragma unroll
        for (int fm = 0; fm < 4; ++fm)
#pragma unroll
          for (int e = 0; e < 4; ++e)
            rowsum[fm] += exp2f(acc[fm][e] * EXP2_SCALE);
      }
    }
    __syncthreads();  // everyone done reading Bs before next stage
  }

  // fold lanehi j-groups; every lane then holds row (fm*16 + lane16)
#pragma unroll
  for (int fm = 0; fm < 4; ++fm) {
    rowsum[fm] += __shfl_xor(rowsum[fm], 16);
    rowsum[fm] += __shfl_xor(rowsum[fm], 32);
  }
  // coalesced store: lane l -> row rowbase + l  (fm = l>>4, lane16 = l&15)
  const float v = (l < 32) ? ((l < 16) ? rowsum[0] : rowsum[1])
                           : ((l < 48) ? rowsum[2] : rowsum[3]);
  partial[cjg * NROW + rowbase + l] = v;
}

// ---------------- final per-row loss + global reduce --------------------
__global__ __launch_bounds__(256) void final_kernel(
    const float* __restrict__ xn, const int* __restrict__ y,
    const float* __restrict__ Sext, const float* __restrict__ partial,
    float* __restrict__ out) {
  const float* S = Sext;
  const float* histf = Sext + NCLS * CDIM;
  const int l = threadIdx.x & 63, w = threadIdx.x >> 6;
  const int waveid = blockIdx.x * 4 + w;  // 0..2047
  float accum = 0.f;
  for (int t = 0; t < 4; ++t) {
    const int row = waveid + 2048 * t;
    // lanes 0-15 hold the 16 col-group partials of this row
    float d = (l < NCJG) ? partial[l * NROW + row] : 0.f;
    const int c = y[row];
    const float2 xv = *(const float2*)&xn[row * CDIM + l * 2];
    const float2 sv = *(const float2*)&S[c * CDIM + l * 2];
    float dot = xv.x * sv.x + xv.y * sv.y;
    float sf = xv.x * xv.x + xv.y * xv.y;
#pragma unroll
    for (int off = 32; off; off >>= 1) {
      d += __shfl_xor(d, off);
      dot += __shfl_xor(dot, off);
      sf += __shfl_xor(sf, off);
    }
    const float cntf = histf[c] - 1.f;
    float row_val = 0.f;
    if (cntf > 0.5f) {
      const float possum = dot - sf;  // exclude self term
      row_val = -(possum * 10.0f - cntf * logf(d)) / cntf;
    }
    accum += row_val;
  }
  __shared__ float bsum[4];
  if (l == 0) bsum[w] = accum;
  __syncthreads();
  if (threadIdx.x == 0)
    atomicAdd(out, bsum[0] + bsum[1] + bsum[2] + bsum[3]);
}

extern "C" void kernel_launch(void* const* d_in, const int* in_sizes, int n_in,
                              void* d_out, int out_size, void* d_ws,
                              size_t ws_size, hipStream_t stream) {
  const float* x = (const float*)d_in[0];
  const int* y = (const int*)d_in[1];
  float* out = (float*)d_out;
  char* ws = (char*)d_ws;

  float* xn = (float*)(ws);                     // 4 MB fp32 normalized
  _Float16* xnh = (_Float16*)(ws + (4 << 20));  // 2 MB f16 normalized
  float* partial = (float*)(ws + (6 << 20));    // 512 KB [16][8192]
  float* pS = (float*)(ws + (8 << 20));         // 2.64 MB [1290][512]
  float* Sext = (float*)(ws + (11 << 20));      // 5.2 KB class sums + hist

  hipMemsetAsync(out, 0, sizeof(float), stream);
  norm_csum_kernel<<<NBCS, 256, 0, stream>>>(x, y, xn, xnh, pS);
  csum2_kernel<<<(NSEXT + 3) / 4, 256, 0, stream>>>(pS, Sext);
  gemm_exp_kernel<<<dim3(NCJG, 32), 256, 0, stream>>>(xnh, partial);
  final_kernel<<<512, 256, 0, stream>>>(xn, y, Sext, partial, out);
}

// Round 10
// 107.065 us; speedup vs baseline: 1.4643x; 1.1143x over previous
//
#include <hip/hip_runtime.h>
#include <hip/hip_bf16.h>

#define NROW 8192
#define CDIM 128
#define NCLS 10
#define NCJG 32            // col-groups (256 cols each)
#define NBCS 512           // norm_csum block count
#define NSEXT (NCLS * CDIM + NCLS)  // 1290: class sums + histogram
// 1/(T*ln2) = 10*log2(e)
#define EXP2_SCALE 14.4269504088896f

typedef _Float16 f16x8 __attribute__((ext_vector_type(8)));
typedef _Float16 f16x2 __attribute__((ext_vector_type(2)));
typedef float f32x4 __attribute__((ext_vector_type(4)));

typedef __attribute__((address_space(1))) const unsigned int gu32;
typedef __attribute__((address_space(3))) unsigned int lu32;

__device__ __forceinline__ void gload_lds16(const _Float16* g, _Float16* l) {
  __builtin_amdgcn_global_load_lds((gu32*)g, (lu32*)l, 16, 0, 0);
}

// ---- fused: normalize -> xn,xnh; class-sum+hist block partials (pS,
// transposed for coalesced stage-2). ----
__global__ __launch_bounds__(256) void norm_csum_kernel(
    const float* __restrict__ x, const int* __restrict__ y,
    float* __restrict__ xn, _Float16* __restrict__ xnh,
    float* __restrict__ pS) {
  __shared__ float s[NCLS * CDIM];
  __shared__ float hcnt[NCLS];
  const int t = threadIdx.x;
  const int l = t & 63, w = t >> 6;
  for (int i = t; i < NCLS * CDIM; i += 256) s[i] = 0.f;
  if (t < NCLS) hcnt[t] = 0.f;
  __syncthreads();
  const int row0 = blockIdx.x * 16 + w * 4;
  float2 v[4];
  int c[4];
#pragma unroll
  for (int r = 0; r < 4; ++r) {
    const int row = row0 + r;
    float2 xv = *(const float2*)&x[row * CDIM + l * 2];
    float ss = xv.x * xv.x + xv.y * xv.y;
#pragma unroll
    for (int off = 32; off; off >>= 1) ss += __shfl_xor(ss, off);
    const float inv = 1.f / fmaxf(sqrtf(ss), 1e-12f);
    xv.x *= inv;
    xv.y *= inv;
    v[r] = xv;
    c[r] = y[row];
    ((float2*)xn)[row * 64 + l] = xv;
    f16x2 h;
    h[0] = (_Float16)xv.x;
    h[1] = (_Float16)xv.y;
    ((f16x2*)xnh)[row * 64 + l] = h;
  }
#pragma unroll
  for (int r = 0; r < 4; ++r) {
    atomicAdd(&s[c[r] * CDIM + l * 2], v[r].x);
    atomicAdd(&s[c[r] * CDIM + l * 2 + 1], v[r].y);
  }
  if (l == 0) {
#pragma unroll
    for (int r = 0; r < 4; ++r) atomicAdd(&hcnt[c[r]], 1.f);
  }
  __syncthreads();
  for (int i = t; i < NCLS * CDIM; i += 256)
    pS[i * NBCS + blockIdx.x] = s[i];
  if (t < NCLS) pS[(NCLS * CDIM + t) * NBCS + blockIdx.x] = hcnt[t];
}

// ---- stage 2: one wave per output (1280 class-sums + 10 hist);
// also zeroes the output scalar (replaces a memset node). ----
__global__ void csum2_kernel(const float* __restrict__ pS,
                             float* __restrict__ Sext,
                             float* __restrict__ out) {
  if (blockIdx.x == 0 && threadIdx.x == 0) *out = 0.f;
  const int w = threadIdx.x >> 6, l = threadIdx.x & 63;
  const int i = blockIdx.x * 4 + w;
  if (i >= NSEXT) return;
  const f32x4* p = (const f32x4*)&pS[i * NBCS];
  const f32x4 v0 = p[l], v1 = p[l + 64];
  float a = v0.x + v0.y + v0.z + v0.w + v1.x + v1.y + v1.z + v1.w;
#pragma unroll
  for (int off = 32; off; off >>= 1) a += __shfl_xor(a, off);
  if (l == 0) Sext[i] = a;
}

// ---- Gram GEMM + exp + row-sum. 1024 blocks (4/CU, 4 waves/SIMD),
// each block = 256 rows x 256 cols = 2 B-tiles looped, single 32KB LDS.
//  * A: each wave owns 64 rows x 128 K in regs, loaded once.
//  * B staged via global_load_lds; XOR swizzle via pre-swizzled source.
//  * fn-invariant ds offsets: (fn*16+lane16)&7 == lane16&7, so the 4
//    per-kk lane offsets are computed ONCE; inner loop is pure
//    ds_read_b128 with immediate offset fn*4096.
//  * SWAPPED MFMA (acc = mfma(b,a)): out col(lane16)=i, row(lanehi,e)=j
//    -> row-sum is in-register; acc chains start from invariant zero.
//  * exp2 via __builtin_amdgcn_exp2f (bare v_exp_f32; args in [-15,15]).
//  * One coalesced 256B store per wave: partial[cjg][rowbase+l]. ----
__global__ __launch_bounds__(256, 4) void gemm_exp_kernel(
    const _Float16* __restrict__ xnh, float* __restrict__ partial) {
  __shared__ _Float16 Bs[128 * 128];

  const int tid = threadIdx.x;
  const int l = tid & 63, w = tid >> 6;
  const int lane16 = l & 15, lanehi = l >> 4;
  const int cjg = blockIdx.x;  // 0..31  (256-col group)
  const int rb = blockIdx.y;   // 0..31  (256-row block)

  // A slab for this wave: rows [rb*256 + w*64, +64), full K in registers
  const int rowbase = rb * 256 + w * 64;
  f16x8 a[4][4];
#pragma unroll
  for (int fm = 0; fm < 4; ++fm) {
    const int ra = rowbase + fm * 16 + lane16;
#pragma unroll
    for (int kk = 0; kk < 4; ++kk)
      a[fm][kk] = *(const f16x8*)&xnh[ra * CDIM + (kk * 4 + lanehi) * 8];
  }

  // fn-invariant per-kk LDS element offsets (within a 16-row group)
  int boff[4];
#pragma unroll
  for (int kk = 0; kk < 4; ++kk)
    boff[kk] = lane16 * 128 + (((kk * 4 + lanehi) ^ (lane16 & 7)) * 8);

  const int myrowblk = rowbase >> 7;
  float rowsum[4] = {0.f, 0.f, 0.f, 0.f};
  const f32x4 z4 = {0.f, 0.f, 0.f, 0.f};

  for (int t = 0; t < 2; ++t) {
    const int cb = cjg * 2 + t;  // global 128-col block
    // stage B tile: 32 x 1KB chunks, 8 per wave
    {
      const _Float16* srcb = xnh + (long)cb * 128 * CDIM;
#pragma unroll
      for (int i = 0; i < 8; ++i) {
        const int rg = (w * 8 + i) * 4;      // first row of 1KB chunk
        const int rl = rg + lanehi;          // row this lane fetches
        const int csrc = lane16 ^ (rl & 7);  // pre-swizzled source chunk
        gload_lds16(&srcb[rl * CDIM + csrc * 8], &Bs[rg * 128]);
      }
    }
    __syncthreads();  // drains vmcnt+lgkmcnt: staged tile visible

    const bool dt = (cb == myrowblk);  // tile touches the diagonal
#pragma unroll
    for (int fn = 0; fn < 8; ++fn) {
      f16x8 b[4];
#pragma unroll
      for (int kk = 0; kk < 4; ++kk)
        b[kk] = *(const f16x8*)&Bs[fn * 2048 + boff[kk]];
      f32x4 acc[4];
#pragma unroll
      for (int kk = 0; kk < 4; ++kk)
#pragma unroll
        for (int fm = 0; fm < 4; ++fm)
          acc[fm] = __builtin_amdgcn_mfma_f32_16x16x32_f16(
              b[kk], a[fm][kk], (kk == 0) ? z4 : acc[fm], 0, 0, 0);
      if (dt) {
#pragma unroll
        for (int fm = 0; fm < 4; ++fm) {
          const int gi = rowbase + fm * 16 + lane16;
          const int j0 = cb * 128 + fn * 16 + lanehi * 4;
#pragma unroll
          for (int e = 0; e < 4; ++e) {
            float vv = __builtin_amdgcn_exp2f(acc[fm][e] * EXP2_SCALE);
            if (gi == (j0 + e)) vv = 0.f;
            rowsum[fm] += vv;
          }
        }
      } else {
#pragma unroll
        for (int fm = 0; fm < 4; ++fm)
#pragma unroll
          for (int e = 0; e < 4; ++e)
            rowsum[fm] += __builtin_amdgcn_exp2f(acc[fm][e] * EXP2_SCALE);
      }
    }
    __syncthreads();  // everyone done reading Bs before next stage
  }

  // fold lanehi j-groups; every lane then holds row (fm*16 + lane16)
#pragma unroll
  for (int fm = 0; fm < 4; ++fm) {
    rowsum[fm] += __shfl_xor(rowsum[fm], 16);
    rowsum[fm] += __shfl_xor(rowsum[fm], 32);
  }
  // coalesced store: lane l -> row rowbase + l  (fm = l>>4, lane16 = l&15)
  const float v = (l < 32) ? ((l < 16) ? rowsum[0] : rowsum[1])
                           : ((l < 48) ? rowsum[2] : rowsum[3]);
  partial[cjg * NROW + rowbase + l] = v;
}

// ---------------- final per-row loss + global reduce --------------------
__global__ __launch_bounds__(256) void final_kernel(
    const float* __restrict__ xn, const int* __restrict__ y,
    const float* __restrict__ Sext, const float* __restrict__ partial,
    float* __restrict__ out) {
  const float* S = Sext;
  const float* histf = Sext + NCLS * CDIM;
  const int l = threadIdx.x & 63, w = threadIdx.x >> 6;
  const int waveid = blockIdx.x * 4 + w;  // 0..2047
  float accum = 0.f;
  for (int t = 0; t < 4; ++t) {
    const int row = waveid + 2048 * t;
    // lanes 0-31 hold the 32 col-group partials of this row
    float d = (l < NCJG) ? partial[l * NROW + row] : 0.f;
    const int c = y[row];
    const float2 xv = *(const float2*)&xn[row * CDIM + l * 2];
    const float2 sv = *(const float2*)&S[c * CDIM + l * 2];
    float dot = xv.x * sv.x + xv.y * sv.y;
    float sf = xv.x * xv.x + xv.y * xv.y;
#pragma unroll
    for (int off = 32; off; off >>= 1) {
      d += __shfl_xor(d, off);
      dot += __shfl_xor(dot, off);
      sf += __shfl_xor(sf, off);
    }
    const float cntf = histf[c] - 1.f;
    float row_val = 0.f;
    if (cntf > 0.5f) {
      const float possum = dot - sf;  // exclude self term
      row_val = -(possum * 10.0f - cntf * logf(d)) / cntf;
    }
    accum += row_val;
  }
  __shared__ float bsum[4];
  if (l == 0) bsum[w] = accum;
  __syncthreads();
  if (threadIdx.x == 0)
    atomicAdd(out, bsum[0] + bsum[1] + bsum[2] + bsum[3]);
}

extern "C" void kernel_launch(void* const* d_in, const int* in_sizes, int n_in,
                              void* d_out, int out_size, void* d_ws,
                              size_t ws_size, hipStream_t stream) {
  const float* x = (const float*)d_in[0];
  const int* y = (const int*)d_in[1];
  float* out = (float*)d_out;
  char* ws = (char*)d_ws;

  float* xn = (float*)(ws);                     // 4 MB fp32 normalized
  _Float16* xnh = (_Float16*)(ws + (4 << 20));  // 2 MB f16 normalized
  float* partial = (float*)(ws + (6 << 20));    // 1 MB [32][8192]
  float* pS = (float*)(ws + (8 << 20));         // 2.64 MB [1290][512]
  float* Sext = (float*)(ws + (11 << 20));      // 5.2 KB class sums + hist

  norm_csum_kernel<<<NBCS, 256, 0, stream>>>(x, y, xn, xnh, pS);
  csum2_kernel<<<(NSEXT + 3) / 4, 256, 0, stream>>>(pS, Sext, out);
  gemm_exp_kernel<<<dim3(NCJG, 32), 256, 0, stream>>>(xnh, partial);
  final_kernel<<<512, 256, 0, stream>>>(xn, y, Sext, partial, out);
}

// Round 11
// 106.775 us; speedup vs baseline: 1.4683x; 1.0027x over previous
//
#include <hip/hip_runtime.h>
#include <hip/hip_bf16.h>

#define NROW 8192
#define CDIM 128
#define NCLS 10
#define NCJG 32            // col-groups (256 cols each, 4x 64-col subtiles)
#define NBCS 512           // norm_csum block count
#define NSEXT (NCLS * CDIM + NCLS)  // 1290: class sums + histogram
// 1/(T*ln2) = 10*log2(e)
#define EXP2_SCALE 14.4269504088896f

typedef _Float16 f16x8 __attribute__((ext_vector_type(8)));
typedef _Float16 f16x2 __attribute__((ext_vector_type(2)));
typedef float f32x4 __attribute__((ext_vector_type(4)));

typedef __attribute__((address_space(1))) const unsigned int gu32;
typedef __attribute__((address_space(3))) unsigned int lu32;

__device__ __forceinline__ void gload_lds16(const _Float16* g, _Float16* l) {
  __builtin_amdgcn_global_load_lds((gu32*)g, (lu32*)l, 16, 0, 0);
}

// ---- fused: normalize -> xnh (f16 only); class-sum + hist block
// partials in fp32 (pS transposed for coalesced stage-2). ----
__global__ __launch_bounds__(256) void norm_csum_kernel(
    const float* __restrict__ x, const int* __restrict__ y,
    _Float16* __restrict__ xnh, float* __restrict__ pS) {
  __shared__ float s[NCLS * CDIM];
  __shared__ float hcnt[NCLS];
  const int t = threadIdx.x;
  const int l = t & 63, w = t >> 6;
  for (int i = t; i < NCLS * CDIM; i += 256) s[i] = 0.f;
  if (t < NCLS) hcnt[t] = 0.f;
  __syncthreads();
  const int row0 = blockIdx.x * 16 + w * 4;
  float2 v[4];
  int c[4];
#pragma unroll
  for (int r = 0; r < 4; ++r) {
    const int row = row0 + r;
    float2 xv = *(const float2*)&x[row * CDIM + l * 2];
    float ss = xv.x * xv.x + xv.y * xv.y;
#pragma unroll
    for (int off = 32; off; off >>= 1) ss += __shfl_xor(ss, off);
    const float inv = 1.f / fmaxf(sqrtf(ss), 1e-12f);
    xv.x *= inv;
    xv.y *= inv;
    v[r] = xv;
    c[r] = y[row];
    f16x2 h;
    h[0] = (_Float16)xv.x;
    h[1] = (_Float16)xv.y;
    ((f16x2*)xnh)[row * 64 + l] = h;
  }
#pragma unroll
  for (int r = 0; r < 4; ++r) {
    atomicAdd(&s[c[r] * CDIM + l * 2], v[r].x);
    atomicAdd(&s[c[r] * CDIM + l * 2 + 1], v[r].y);
  }
  if (l == 0) {
#pragma unroll
    for (int r = 0; r < 4; ++r) atomicAdd(&hcnt[c[r]], 1.f);
  }
  __syncthreads();
  for (int i = t; i < NCLS * CDIM; i += 256)
    pS[i * NBCS + blockIdx.x] = s[i];
  if (t < NCLS) pS[(NCLS * CDIM + t) * NBCS + blockIdx.x] = hcnt[t];
}

// ---- stage 2: one wave per output (1280 class-sums + 10 hist);
// also zeroes the output scalar (replaces a memset node). ----
__global__ void csum2_kernel(const float* __restrict__ pS,
                             float* __restrict__ Sext,
                             float* __restrict__ out) {
  if (blockIdx.x == 0 && threadIdx.x == 0) *out = 0.f;
  const int w = threadIdx.x >> 6, l = threadIdx.x & 63;
  const int i = blockIdx.x * 4 + w;
  if (i >= NSEXT) return;
  const f32x4* p = (const f32x4*)&pS[i * NBCS];
  const f32x4 v0 = p[l], v1 = p[l + 64];
  float a = v0.x + v0.y + v0.z + v0.w + v1.x + v1.y + v1.z + v1.w;
#pragma unroll
  for (int off = 32; off; off >>= 1) a += __shfl_xor(a, off);
  if (l == 0) Sext[i] = a;
}

// ---- Gram GEMM + exp + row-sum. 1024 blocks (4/CU), block = 256 rows x
// 256 cols processed as 4x 64-col subtiles, DOUBLE-BUFFERED (T3 2-phase):
// STAGE(buf^1, s+1) issued BEFORE computing buf[s]; one barrier/subtile,
// so the 16KB stage hides under 64 MFMA + epilogue. LDS = 2x16KB = 32KB
// (occupancy unchanged).
//  * A: each wave owns 64 rows x 128 K in regs, loaded once.
//  * B staged via global_load_lds; XOR swizzle via pre-swizzled source;
//    fn-invariant read offsets (4 per-lane, computed once).
//  * SWAPPED MFMA (acc = mfma(b,a)): out col(lane16)=i, row(lanehi,e)=j
//    -> row-sum is in-register; acc chains start from invariant zero.
//  * exp2 via __builtin_amdgcn_exp2f (args in [-14.5, 14.5]).
//  * One coalesced 256B store per wave: partial[cjg][rowbase+l]. ----
__global__ __launch_bounds__(256, 4) void gemm_exp_kernel(
    const _Float16* __restrict__ xnh, float* __restrict__ partial) {
  __shared__ _Float16 Bs[2][64 * 128];

  const int tid = threadIdx.x;
  const int l = tid & 63, w = tid >> 6;
  const int lane16 = l & 15, lanehi = l >> 4;
  const int cjg = blockIdx.x;  // 0..31  (256-col group)
  const int rb = blockIdx.y;   // 0..31  (256-row block)
  const int rowbase = rb * 256 + w * 64;

  // stage 64-col subtile s (16KB): 16 x 1KB chunks, 4 per wave
#define STAGE(buf, s)                                                   \
  {                                                                     \
    const _Float16* srcb = xnh + (long)(cjg * 4 + (s)) * 64 * CDIM;     \
    _Float16* dstb = Bs[buf];                                           \
    _Pragma("unroll") for (int i = 0; i < 4; ++i) {                     \
      const int rg = (w * 4 + i) * 4;                                   \
      const int rl = rg + lanehi;                                       \
      const int csrc = lane16 ^ (rl & 7);                               \
      gload_lds16(&srcb[rl * CDIM + csrc * 8], &dstb[rg * 128]);        \
    }                                                                   \
  }

  STAGE(0, 0);  // prologue: first subtile in flight

  // A slab for this wave: rows [rowbase, +64), full K in registers
  f16x8 a[4][4];
#pragma unroll
  for (int fm = 0; fm < 4; ++fm) {
    const int ra = rowbase + fm * 16 + lane16;
#pragma unroll
    for (int kk = 0; kk < 4; ++kk)
      a[fm][kk] = *(const f16x8*)&xnh[ra * CDIM + (kk * 4 + lanehi) * 8];
  }

  // fn-invariant per-kk LDS element offsets (within a 16-row group)
  int boff[4];
#pragma unroll
  for (int kk = 0; kk < 4; ++kk)
    boff[kk] = lane16 * 128 + (((kk * 4 + lanehi) ^ (lane16 & 7)) * 8);

  const int myrow64 = rowbase >> 6;  // 64-col block containing our rows
  float rowsum[4] = {0.f, 0.f, 0.f, 0.f};
  const f32x4 z4 = {0.f, 0.f, 0.f, 0.f};

  __syncthreads();  // subtile 0 staged (vmcnt+lgkm drained by barrier)

#pragma unroll
  for (int s = 0; s < 4; ++s) {
    if (s < 3) STAGE((s + 1) & 1, s + 1);  // prefetch next subtile
    const int cb64 = cjg * 4 + s;
    const bool dt = (cb64 == myrow64);  // subtile touches the diagonal
    const _Float16* B = Bs[s & 1];
#pragma unroll
    for (int fn = 0; fn < 4; ++fn) {
      f16x8 b[4];
#pragma unroll
      for (int kk = 0; kk < 4; ++kk)
        b[kk] = *(const f16x8*)&B[fn * 2048 + boff[kk]];
      f32x4 acc[4];
#pragma unroll
      for (int kk = 0; kk < 4; ++kk)
#pragma unroll
        for (int fm = 0; fm < 4; ++fm)
          acc[fm] = __builtin_amdgcn_mfma_f32_16x16x32_f16(
              b[kk], a[fm][kk], (kk == 0) ? z4 : acc[fm], 0, 0, 0);
      if (dt) {
#pragma unroll
        for (int fm = 0; fm < 4; ++fm) {
          const int gi = rowbase + fm * 16 + lane16;
          const int j0 = cb64 * 64 + fn * 16 + lanehi * 4;
#pragma unroll
          for (int e = 0; e < 4; ++e) {
            float vv = __builtin_amdgcn_exp2f(acc[fm][e] * EXP2_SCALE);
            if (gi == (j0 + e)) vv = 0.f;
            rowsum[fm] += vv;
          }
        }
      } else {
#pragma unroll
        for (int fm = 0; fm < 4; ++fm)
#pragma unroll
          for (int e = 0; e < 4; ++e)
            rowsum[fm] += __builtin_amdgcn_exp2f(acc[fm][e] * EXP2_SCALE);
      }
    }
    __syncthreads();  // stage s+1 complete; all waves done reading buf s
  }
#undef STAGE

  // fold lanehi j-groups; every lane then holds row (fm*16 + lane16)
#pragma unroll
  for (int fm = 0; fm < 4; ++fm) {
    rowsum[fm] += __shfl_xor(rowsum[fm], 16);
    rowsum[fm] += __shfl_xor(rowsum[fm], 32);
  }
  // coalesced store: lane l -> row rowbase + l  (fm = l>>4, lane16 = l&15)
  const float v = (l < 32) ? ((l < 16) ? rowsum[0] : rowsum[1])
                           : ((l < 48) ? rowsum[2] : rowsum[3]);
  partial[cjg * NROW + rowbase + l] = v;
}

// ---------------- final per-row loss + global reduce --------------------
// Reads the f16 normalized features (no fp32 xn round-trip).
__global__ __launch_bounds__(256) void final_kernel(
    const _Float16* __restrict__ xnh, const int* __restrict__ y,
    const float* __restrict__ Sext, const float* __restrict__ partial,
    float* __restrict__ out) {
  const float* S = Sext;
  const float* histf = Sext + NCLS * CDIM;
  const int l = threadIdx.x & 63, w = threadIdx.x >> 6;
  const int waveid = blockIdx.x * 4 + w;  // 0..2047
  float accum = 0.f;
  for (int t = 0; t < 4; ++t) {
    const int row = waveid + 2048 * t;
    // lanes 0-31 hold the 32 col-group partials of this row
    float d = (l < NCJG) ? partial[l * NROW + row] : 0.f;
    const int c = y[row];
    const f16x2 hv = ((const f16x2*)xnh)[row * 64 + l];
    const float2 sv = *(const float2*)&S[c * CDIM + l * 2];
    const float x0 = (float)hv[0], x1 = (float)hv[1];
    float dot = x0 * sv.x + x1 * sv.y;
    float sf = x0 * x0 + x1 * x1;
#pragma unroll
    for (int off = 32; off; off >>= 1) {
      d += __shfl_xor(d, off);
      dot += __shfl_xor(dot, off);
      sf += __shfl_xor(sf, off);
    }
    const float cntf = histf[c] - 1.f;
    float row_val = 0.f;
    if (cntf > 0.5f) {
      const float possum = dot - sf;  // exclude self term
      row_val = -(possum * 10.0f - cntf * logf(d)) / cntf;
    }
    accum += row_val;
  }
  __shared__ float bsum[4];
  if (l == 0) bsum[w] = accum;
  __syncthreads();
  if (threadIdx.x == 0)
    atomicAdd(out, bsum[0] + bsum[1] + bsum[2] + bsum[3]);
}

extern "C" void kernel_launch(void* const* d_in, const int* in_sizes, int n_in,
                              void* d_out, int out_size, void* d_ws,
                              size_t ws_size, hipStream_t stream) {
  const float* x = (const float*)d_in[0];
  const int* y = (const int*)d_in[1];
  float* out = (float*)d_out;
  char* ws = (char*)d_ws;

  _Float16* xnh = (_Float16*)(ws);             // 2 MB f16 normalized
  float* partial = (float*)(ws + (2 << 20));   // 1 MB [32][8192]
  float* pS = (float*)(ws + (4 << 20));        // 2.64 MB [1290][512]
  float* Sext = (float*)(ws + (7 << 20));      // 5.2 KB class sums + hist

  norm_csum_kernel<<<NBCS, 256, 0, stream>>>(x, y, xnh, pS);
  csum2_kernel<<<(NSEXT + 3) / 4, 256, 0, stream>>>(pS, Sext, out);
  gemm_exp_kernel<<<dim3(NCJG, 32), 256, 0, stream>>>(xnh, partial);
  final_kernel<<<512, 256, 0, stream>>>(xnh, y, Sext, partial, out);
}

// Round 12
// 105.536 us; speedup vs baseline: 1.4855x; 1.0117x over previous
//
#include <hip/hip_runtime.h>
#include <hip/hip_bf16.h>

#define NROW 8192
#define CDIM 128
#define NCLS 10
#define NCJG 32            // col-groups (256 cols each, 4x 64-col subtiles)
#define NBCS 512           // norm_csum block count
#define NSEXT (NCLS * CDIM + NCLS)  // 1290: class sums + histogram
// 1/(T*ln2) = 10*log2(e)
#define EXP2_SCALE 14.4269504088896f

typedef _Float16 f16x8 __attribute__((ext_vector_type(8)));
typedef _Float16 f16x2 __attribute__((ext_vector_type(2)));
typedef float f32x4 __attribute__((ext_vector_type(4)));

typedef __attribute__((address_space(1))) const unsigned int gu32;
typedef __attribute__((address_space(3))) unsigned int lu32;

__device__ __forceinline__ void gload_lds16(const _Float16* g, _Float16* l) {
  __builtin_amdgcn_global_load_lds((gu32*)g, (lu32*)l, 16, 0, 0);
}

// ---- fused: normalize -> xnh (f16 only); class-sum + hist block
// partials in fp32 (pS transposed for coalesced stage-2). ----
__global__ __launch_bounds__(256) void norm_csum_kernel(
    const float* __restrict__ x, const int* __restrict__ y,
    _Float16* __restrict__ xnh, float* __restrict__ pS) {
  __shared__ float s[NCLS * CDIM];
  __shared__ float hcnt[NCLS];
  const int t = threadIdx.x;
  const int l = t & 63, w = t >> 6;
  for (int i = t; i < NCLS * CDIM; i += 256) s[i] = 0.f;
  if (t < NCLS) hcnt[t] = 0.f;
  __syncthreads();
  const int row0 = blockIdx.x * 16 + w * 4;
  float2 v[4];
  int c[4];
#pragma unroll
  for (int r = 0; r < 4; ++r) {
    const int row = row0 + r;
    float2 xv = *(const float2*)&x[row * CDIM + l * 2];
    float ss = xv.x * xv.x + xv.y * xv.y;
#pragma unroll
    for (int off = 32; off; off >>= 1) ss += __shfl_xor(ss, off);
    const float inv = 1.f / fmaxf(sqrtf(ss), 1e-12f);
    xv.x *= inv;
    xv.y *= inv;
    v[r] = xv;
    c[r] = y[row];
    f16x2 h;
    h[0] = (_Float16)xv.x;
    h[1] = (_Float16)xv.y;
    ((f16x2*)xnh)[row * 64 + l] = h;
  }
#pragma unroll
  for (int r = 0; r < 4; ++r) {
    atomicAdd(&s[c[r] * CDIM + l * 2], v[r].x);
    atomicAdd(&s[c[r] * CDIM + l * 2 + 1], v[r].y);
  }
  if (l == 0) {
#pragma unroll
    for (int r = 0; r < 4; ++r) atomicAdd(&hcnt[c[r]], 1.f);
  }
  __syncthreads();
  for (int i = t; i < NCLS * CDIM; i += 256)
    pS[i * NBCS + blockIdx.x] = s[i];
  if (t < NCLS) pS[(NCLS * CDIM + t) * NBCS + blockIdx.x] = hcnt[t];
}

// ---- stage 2: one wave per output (1280 class-sums + 10 hist);
// also zeroes the output scalar (replaces a memset node). ----
__global__ void csum2_kernel(const float* __restrict__ pS,
                             float* __restrict__ Sext,
                             float* __restrict__ out) {
  if (blockIdx.x == 0 && threadIdx.x == 0) *out = 0.f;
  const int w = threadIdx.x >> 6, l = threadIdx.x & 63;
  const int i = blockIdx.x * 4 + w;
  if (i >= NSEXT) return;
  const f32x4* p = (const f32x4*)&pS[i * NBCS];
  const f32x4 v0 = p[l], v1 = p[l + 64];
  float a = v0.x + v0.y + v0.z + v0.w + v1.x + v1.y + v1.z + v1.w;
#pragma unroll
  for (int off = 32; off; off >>= 1) a += __shfl_xor(a, off);
  if (l == 0) Sext[i] = a;
}

// ---- Gram GEMM + exp + row-sum. 1024 blocks (4/CU), block = 256 rows x
// 256 cols as 4x 64-col subtiles, double-buffered LDS (2x16KB).
//  * A: each wave owns 64 rows x 128 K in regs, loaded once and PINNED
//    via asm ("+v") so the compiler cannot rematerialize the loads into
//    the subtile loop (r10/r11 VGPR_Count=64 proved A was NOT resident:
//    a[4][4] alone is 64 VGPRs, +b[4]=16 live under MFMA => >=80 min).
//  * B staged via global_load_lds; XOR swizzle via pre-swizzled source;
//    fn-invariant read offsets (4 per-lane, computed once).
//  * SWAPPED MFMA (acc = mfma(b,a)): out col(lane16)=i, row(lanehi,e)=j
//    -> row-sum is in-register; acc chains start from invariant zero.
//  * exp2 via __builtin_amdgcn_exp2f (args in [-14.5, 14.5]).
//  * One coalesced 256B store per wave: partial[cjg][rowbase+l]. ----
__global__ __launch_bounds__(256, 4) void gemm_exp_kernel(
    const _Float16* __restrict__ xnh, float* __restrict__ partial) {
  __shared__ _Float16 Bs[2][64 * 128];

  const int tid = threadIdx.x;
  const int l = tid & 63, w = tid >> 6;
  const int lane16 = l & 15, lanehi = l >> 4;
  const int cjg = blockIdx.x;  // 0..31  (256-col group)
  const int rb = blockIdx.y;   // 0..31  (256-row block)
  const int rowbase = rb * 256 + w * 64;

  // stage 64-col subtile s (16KB): 16 x 1KB chunks, 4 per wave
#define STAGE(buf, s)                                                   \
  {                                                                     \
    const _Float16* srcb = xnh + (long)(cjg * 4 + (s)) * 64 * CDIM;     \
    _Float16* dstb = Bs[buf];                                           \
    _Pragma("unroll") for (int i = 0; i < 4; ++i) {                     \
      const int rg = (w * 4 + i) * 4;                                   \
      const int rl = rg + lanehi;                                       \
      const int csrc = lane16 ^ (rl & 7);                               \
      gload_lds16(&srcb[rl * CDIM + csrc * 8], &dstb[rg * 128]);        \
    }                                                                   \
  }

  STAGE(0, 0);  // prologue: first subtile in flight

  // A slab for this wave: rows [rowbase, +64), full K in registers
  f16x8 a[4][4];
#pragma unroll
  for (int fm = 0; fm < 4; ++fm) {
    const int ra = rowbase + fm * 16 + lane16;
#pragma unroll
    for (int kk = 0; kk < 4; ++kk)
      a[fm][kk] = *(const f16x8*)&xnh[ra * CDIM + (kk * 4 + lanehi) * 8];
  }
  // PIN A: asm "modifies" each frag -> rematerialization is illegal,
  // the 64 VGPRs stay resident for the whole kernel.
#pragma unroll
  for (int fm = 0; fm < 4; ++fm)
#pragma unroll
    for (int kk = 0; kk < 4; ++kk)
      asm volatile("" : "+v"(a[fm][kk]));

  // fn-invariant per-kk LDS element offsets (within a 16-row group)
  int boff[4];
#pragma unroll
  for (int kk = 0; kk < 4; ++kk)
    boff[kk] = lane16 * 128 + (((kk * 4 + lanehi) ^ (lane16 & 7)) * 8);

  const int myrow64 = rowbase >> 6;  // 64-col block containing our rows
  float rowsum[4] = {0.f, 0.f, 0.f, 0.f};
  const f32x4 z4 = {0.f, 0.f, 0.f, 0.f};

  __syncthreads();  // subtile 0 staged (vmcnt+lgkm drained by barrier)

#pragma unroll
  for (int s = 0; s < 4; ++s) {
    if (s < 3) STAGE((s + 1) & 1, s + 1);  // prefetch next subtile
    const int cb64 = cjg * 4 + s;
    const bool dt = (cb64 == myrow64);  // subtile touches the diagonal
    const _Float16* B = Bs[s & 1];
#pragma unroll
    for (int fn = 0; fn < 4; ++fn) {
      f16x8 b[4];
#pragma unroll
      for (int kk = 0; kk < 4; ++kk)
        b[kk] = *(const f16x8*)&B[fn * 2048 + boff[kk]];
      f32x4 acc[4];
#pragma unroll
      for (int kk = 0; kk < 4; ++kk)
#pragma unroll
        for (int fm = 0; fm < 4; ++fm)
          acc[fm] = __builtin_amdgcn_mfma_f32_16x16x32_f16(
              b[kk], a[fm][kk], (kk == 0) ? z4 : acc[fm], 0, 0, 0);
      if (dt) {
#pragma unroll
        for (int fm = 0; fm < 4; ++fm) {
          const int gi = rowbase + fm * 16 + lane16;
          const int j0 = cb64 * 64 + fn * 16 + lanehi * 4;
#pragma unroll
          for (int e = 0; e < 4; ++e) {
            float vv = __builtin_amdgcn_exp2f(acc[fm][e] * EXP2_SCALE);
            if (gi == (j0 + e)) vv = 0.f;
            rowsum[fm] += vv;
          }
        }
      } else {
#pragma unroll
        for (int fm = 0; fm < 4; ++fm)
#pragma unroll
          for (int e = 0; e < 4; ++e)
            rowsum[fm] += __builtin_amdgcn_exp2f(acc[fm][e] * EXP2_SCALE);
      }
    }
    __syncthreads();  // stage s+1 complete; all waves done reading buf s
  }
#undef STAGE

  // fold lanehi j-groups; every lane then holds row (fm*16 + lane16)
#pragma unroll
  for (int fm = 0; fm < 4; ++fm) {
    rowsum[fm] += __shfl_xor(rowsum[fm], 16);
    rowsum[fm] += __shfl_xor(rowsum[fm], 32);
  }
  // coalesced store: lane l -> row rowbase + l  (fm = l>>4, lane16 = l&15)
  const float v = (l < 32) ? ((l < 16) ? rowsum[0] : rowsum[1])
                           : ((l < 48) ? rowsum[2] : rowsum[3]);
  partial[cjg * NROW + rowbase + l] = v;
}

// ---------------- final per-row loss + global reduce --------------------
// Reads the f16 normalized features (no fp32 xn round-trip).
__global__ __launch_bounds__(256) void final_kernel(
    const _Float16* __restrict__ xnh, const int* __restrict__ y,
    const float* __restrict__ Sext, const float* __restrict__ partial,
    float* __restrict__ out) {
  const float* S = Sext;
  const float* histf = Sext + NCLS * CDIM;
  const int l = threadIdx.x & 63, w = threadIdx.x >> 6;
  const int waveid = blockIdx.x * 4 + w;  // 0..2047
  float accum = 0.f;
  for (int t = 0; t < 4; ++t) {
    const int row = waveid + 2048 * t;
    // lanes 0-31 hold the 32 col-group partials of this row
    float d = (l < NCJG) ? partial[l * NROW + row] : 0.f;
    const int c = y[row];
    const f16x2 hv = ((const f16x2*)xnh)[row * 64 + l];
    const float2 sv = *(const float2*)&S[c * CDIM + l * 2];
    const float x0 = (float)hv[0], x1 = (float)hv[1];
    float dot = x0 * sv.x + x1 * sv.y;
    float sf = x0 * x0 + x1 * x1;
#pragma unroll
    for (int off = 32; off; off >>= 1) {
      d += __shfl_xor(d, off);
      dot += __shfl_xor(dot, off);
      sf += __shfl_xor(sf, off);
    }
    const float cntf = histf[c] - 1.f;
    float row_val = 0.f;
    if (cntf > 0.5f) {
      const float possum = dot - sf;  // exclude self term
      row_val = -(possum * 10.0f - cntf * logf(d)) / cntf;
    }
    accum += row_val;
  }
  __shared__ float bsum[4];
  if (l == 0) bsum[w] = accum;
  __syncthreads();
  if (threadIdx.x == 0)
    atomicAdd(out, bsum[0] + bsum[1] + bsum[2] + bsum[3]);
}

extern "C" void kernel_launch(void* const* d_in, const int* in_sizes, int n_in,
                              void* d_out, int out_size, void* d_ws,
                              size_t ws_size, hipStream_t stream) {
  const float* x = (const float*)d_in[0];
  const int* y = (const int*)d_in[1];
  float* out = (float*)d_out;
  char* ws = (char*)d_ws;

  _Float16* xnh = (_Float16*)(ws);             // 2 MB f16 normalized
  float* partial = (float*)(ws + (2 << 20));   // 1 MB [32][8192]
  float* pS = (float*)(ws + (4 << 20));        // 2.64 MB [1290][512]
  float* Sext = (float*)(ws + (7 << 20));      // 5.2 KB class sums + hist

  norm_csum_kernel<<<NBCS, 256, 0, stream>>>(x, y, xnh, pS);
  csum2_kernel<<<(NSEXT + 3) / 4, 256, 0, stream>>>(pS, Sext, out);
  gemm_exp_kernel<<<dim3(NCJG, 32), 256, 0, stream>>>(xnh, partial);
  final_kernel<<<512, 256, 0, stream>>>(xnh, y, Sext, partial, out);
}

// Round 15
// 102.821 us; speedup vs baseline: 1.5247x; 1.0264x over previous
//
#include <hip/hip_runtime.h>
#include <hip/hip_bf16.h>

#define NROW 8192
#define CDIM 128
#define NCLS 10
#define NCJG 32            // col-groups (256 cols each, 4x 64-col subtiles)
#define NBCS 512           // norm_csum block count
#define NSEXT (NCLS * CDIM + NCLS)  // 1290: class sums + histogram
// 1/(T*ln2) = 10*log2(e)
#define EXP2_SCALE 14.4269504088896f

typedef _Float16 f16x8 __attribute__((ext_vector_type(8)));
typedef _Float16 f16x2 __attribute__((ext_vector_type(2)));
typedef float f32x4 __attribute__((ext_vector_type(4)));

typedef __attribute__((address_space(1))) const unsigned int gu32;
typedef __attribute__((address_space(3))) unsigned int lu32;

__device__ __forceinline__ void gload_lds16(const _Float16* g, _Float16* l) {
  __builtin_amdgcn_global_load_lds((gu32*)g, (lu32*)l, 16, 0, 0);
}

// ---- fused: normalize -> xnh (f16); class-sum + hist block partials
// (pS transposed for coalesced stage-2); zero the out scalar. ----
__global__ __launch_bounds__(256) void norm_csum_kernel(
    const float* __restrict__ x, const int* __restrict__ y,
    _Float16* __restrict__ xnh, float* __restrict__ pS,
    float* __restrict__ out) {
  __shared__ float s[NCLS * CDIM];
  __shared__ float hcnt[NCLS];
  const int t = threadIdx.x;
  const int l = t & 63, w = t >> 6;
  for (int i = t; i < NCLS * CDIM; i += 256) s[i] = 0.f;
  if (t < NCLS) hcnt[t] = 0.f;
  if (blockIdx.x == 0 && t == 0) *out = 0.f;
  __syncthreads();
  const int row0 = blockIdx.x * 16 + w * 4;
  float2 v[4];
  int c[4];
#pragma unroll
  for (int r = 0; r < 4; ++r) {
    const int row = row0 + r;
    float2 xv = *(const float2*)&x[row * CDIM + l * 2];
    float ss = xv.x * xv.x + xv.y * xv.y;
#pragma unroll
    for (int off = 32; off; off >>= 1) ss += __shfl_xor(ss, off);
    const float inv = 1.f / fmaxf(sqrtf(ss), 1e-12f);
    xv.x *= inv;
    xv.y *= inv;
    v[r] = xv;
    c[r] = y[row];
    f16x2 h;
    h[0] = (_Float16)xv.x;
    h[1] = (_Float16)xv.y;
    ((f16x2*)xnh)[row * 64 + l] = h;
  }
#pragma unroll
  for (int r = 0; r < 4; ++r) {
    atomicAdd(&s[c[r] * CDIM + l * 2], v[r].x);
    atomicAdd(&s[c[r] * CDIM + l * 2 + 1], v[r].y);
  }
  if (l == 0) {
#pragma unroll
    for (int r = 0; r < 4; ++r) atomicAdd(&hcnt[c[r]], 1.f);
  }
  __syncthreads();
  for (int i = t; i < NCLS * CDIM; i += 256)
    pS[i * NBCS + blockIdx.x] = s[i];
  if (t < NCLS) pS[(NCLS * CDIM + t) * NBCS + blockIdx.x] = hcnt[t];
}

// ---- Gram GEMM + exp + row-sum, with csum2 fused into the prologue.
// 512 blocks x 512 thr (8 waves) = exactly 2 blocks/CU (launch_bounds
// (512,4): 8 waves x 4/EU -> 2 blocks/CU; LDS 2x32KB = 64KB/CU; same
// 16 waves/CU as r12 but HALF the barrier-drain events per CU).
// Block = 512 rows x 256 cols as 4x 64-col subtiles, double-buffered.
//  * prologue (blocks 0..161): wave i=blk*8+w reduces pS -> Sext,
//    overlapping the first async B-stage.
//  * A: each wave owns 64 rows x 128 K in regs, loaded once, pinned.
//  * B staged via global_load_lds; XOR swizzle via pre-swizzled source;
//    fn-invariant read offsets.
//  * SWAPPED MFMA (acc = mfma(b,a)): out col(lane16)=i, row(lanehi,e)=j
//    -> row-sum over j is in-register; acc chains start from zero.
//  * One coalesced 256B store per wave: partial[cjg][rowbase+l]. ----
__global__ __launch_bounds__(512, 4) void gemm_exp_kernel(
    const _Float16* __restrict__ xnh, const float* __restrict__ pS,
    float* __restrict__ Sext, float* __restrict__ partial) {
  __shared__ _Float16 Bs[2][64 * 128];

  const int blk = blockIdx.x;
  const int tid = threadIdx.x;
  const int l = tid & 63, w = tid >> 6;  // w: 0..7
  const int lane16 = l & 15, lanehi = l >> 4;
  const int cjg = blk & 31;   // 256-col group
  const int rb = blk >> 5;    // 0..15, 512-row block
  const int rowbase = rb * 512 + w * 64;

  // stage 64-col subtile s (16KB): 16 x 1KB chunks, 2 per wave
#define STAGE(buf, sIdx)                                                \
  {                                                                     \
    const _Float16* srcb = xnh + (long)(cjg * 4 + (sIdx)) * 64 * CDIM;  \
    _Float16* dstb = Bs[buf];                                           \
    _Pragma("unroll") for (int i = 0; i < 2; ++i) {                     \
      const int rg = (w * 2 + i) * 4;                                   \
      const int rl = rg + lanehi;                                       \
      const int csrc = lane16 ^ (rl & 7);                               \
      gload_lds16(&srcb[rl * CDIM + csrc * 8], &dstb[rg * 128]);        \
    }                                                                   \
  }

  STAGE(0, 0);  // prologue: first subtile in flight

  // fused csum2: one wave per output, overlaps the staging latency
  {
    const int i = blk * 8 + w;
    if (i < NSEXT) {
      const f32x4* p = (const f32x4*)&pS[(long)i * NBCS];
      const f32x4 v0 = p[l], v1 = p[l + 64];
      float a = v0.x + v0.y + v0.z + v0.w + v1.x + v1.y + v1.z + v1.w;
#pragma unroll
      for (int off = 32; off; off >>= 1) a += __shfl_xor(a, off);
      if (l == 0) Sext[i] = a;
    }
  }

  // A slab: rows [rowbase, +64), full K in registers, pinned
  f16x8 a[4][4];
#pragma unroll
  for (int fm = 0; fm < 4; ++fm) {
    const int ra = rowbase + fm * 16 + lane16;
#pragma unroll
    for (int kk = 0; kk < 4; ++kk)
      a[fm][kk] = *(const f16x8*)&xnh[ra * CDIM + (kk * 4 + lanehi) * 8];
  }
#pragma unroll
  for (int fm = 0; fm < 4; ++fm)
#pragma unroll
    for (int kk = 0; kk < 4; ++kk) asm volatile("" : "+v"(a[fm][kk]));

  // fn-invariant per-kk LDS element offsets (within a 16-row group)
  int boff[4];
#pragma unroll
  for (int kk = 0; kk < 4; ++kk)
    boff[kk] = lane16 * 128 + (((kk * 4 + lanehi) ^ (lane16 & 7)) * 8);

  const int myrow64 = rowbase >> 6;
  float rowsum[4] = {0.f, 0.f, 0.f, 0.f};
  const f32x4 z4 = {0.f, 0.f, 0.f, 0.f};

  __syncthreads();  // subtile 0 staged

#pragma unroll
  for (int sIdx = 0; sIdx < 4; ++sIdx) {
    if (sIdx < 3) STAGE((sIdx + 1) & 1, sIdx + 1);
    const int cb64 = cjg * 4 + sIdx;
    const bool dt = (cb64 == myrow64);
    const _Float16* B = Bs[sIdx & 1];
#pragma unroll
    for (int fn = 0; fn < 4; ++fn) {
      f16x8 b[4];
#pragma unroll
      for (int kk = 0; kk < 4; ++kk)
        b[kk] = *(const f16x8*)&B[fn * 2048 + boff[kk]];
      f32x4 acc[4];
#pragma unroll
      for (int kk = 0; kk < 4; ++kk)
#pragma unroll
        for (int fm = 0; fm < 4; ++fm)
          acc[fm] = __builtin_amdgcn_mfma_f32_16x16x32_f16(
              b[kk], a[fm][kk], (kk == 0) ? z4 : acc[fm], 0, 0, 0);
      if (dt) {
#pragma unroll
        for (int fm = 0; fm < 4; ++fm) {
          const int gi = rowbase + fm * 16 + lane16;
          const int j0 = cb64 * 64 + fn * 16 + lanehi * 4;
#pragma unroll
          for (int e = 0; e < 4; ++e) {
            float vv = __builtin_amdgcn_exp2f(acc[fm][e] * EXP2_SCALE);
            if (gi == (j0 + e)) vv = 0.f;
            rowsum[fm] += vv;
          }
        }
      } else {
#pragma unroll
        for (int fm = 0; fm < 4; ++fm)
#pragma unroll
          for (int e = 0; e < 4; ++e)
            rowsum[fm] += __builtin_amdgcn_exp2f(acc[fm][e] * EXP2_SCALE);
      }
    }
    __syncthreads();  // stage sIdx+1 complete; all waves done with buf
  }
#undef STAGE

  // fold lanehi j-groups; every lane then holds row (fm*16 + lane16)
#pragma unroll
  for (int fm = 0; fm < 4; ++fm) {
    rowsum[fm] += __shfl_xor(rowsum[fm], 16);
    rowsum[fm] += __shfl_xor(rowsum[fm], 32);
  }
  // coalesced store: lane l -> row rowbase + l
  const float v = (l < 32) ? ((l < 16) ? rowsum[0] : rowsum[1])
                           : ((l < 48) ? rowsum[2] : rowsum[3]);
  partial[cjg * NROW + rowbase + l] = v;
}

// ---------------- final per-row loss + global reduce --------------------
__global__ __launch_bounds__(256) void final_kernel(
    const _Float16* __restrict__ xnh, const int* __restrict__ y,
    const float* __restrict__ Sext, const float* __restrict__ partial,
    float* __restrict__ out) {
  const float* S = Sext;
  const float* histf = Sext + NCLS * CDIM;
  const int l = threadIdx.x & 63, w = threadIdx.x >> 6;
  const int waveid = blockIdx.x * 4 + w;  // 0..2047
  float accum = 0.f;
  for (int t = 0; t < 4; ++t) {
    const int row = waveid + 2048 * t;
    float d = (l < NCJG) ? partial[l * NROW + row] : 0.f;
    const int c = y[row];
    const f16x2 hv = ((const f16x2*)xnh)[row * 64 + l];
    const float2 sv = *(const float2*)&S[c * CDIM + l * 2];
    const float x0 = (float)hv[0], x1 = (float)hv[1];
    float dot = x0 * sv.x + x1 * sv.y;
    float sf = x0 * x0 + x1 * x1;
#pragma unroll
    for (int off = 32; off; off >>= 1) {
      d += __shfl_xor(d, off);
      dot += __shfl_xor(dot, off);
      sf += __shfl_xor(sf, off);
    }
    const float cntf = histf[c] - 1.f;
    if (cntf > 0.5f) {
      const float possum = dot - sf;  // exclude self term
      const float logd = __log2f(d) * 0.6931471805599453f;
      accum += -(possum * 10.0f - cntf * logd) / cntf;
    }
  }
  __shared__ float bsum[4];
  if (l == 0) bsum[w] = accum;
  __syncthreads();
  if (threadIdx.x == 0)
    atomicAdd(out, bsum[0] + bsum[1] + bsum[2] + bsum[3]);
}

extern "C" void kernel_launch(void* const* d_in, const int* in_sizes, int n_in,
                              void* d_out, int out_size, void* d_ws,
                              size_t ws_size, hipStream_t stream) {
  const float* x = (const float*)d_in[0];
  const int* y = (const int*)d_in[1];
  float* out = (float*)d_out;
  char* ws = (char*)d_ws;

  _Float16* xnh = (_Float16*)(ws);             // 2 MB f16 normalized
  float* partial = (float*)(ws + (2 << 20));   // 1 MB [32][8192]
  float* pS = (float*)(ws + (4 << 20));        // 2.64 MB [1290][512]
  float* Sext = (float*)(ws + (7 << 20));      // 5.2 KB class sums + hist

  norm_csum_kernel<<<NBCS, 256, 0, stream>>>(x, y, xnh, pS, out);
  gemm_exp_kernel<<<512, 512, 0, stream>>>(xnh, pS, Sext, partial);
  final_kernel<<<512, 256, 0, stream>>>(xnh, y, Sext, partial, out);
}